// Round 12
// baseline (247.765 us; speedup 1.0000x reference)
//
#include <hip/hip_runtime.h>
#include <math.h>

// Problem dims (fixed by setup_inputs)
constexpr int Bc = 64;
constexpr int Tc = 1000;
constexpr int Vc = 512;
constexpr int Uc = 256;
constexpr int CH = 50;        // t-rows per LDS chunk (scan)
constexpr int NCH = Tc / CH;  // 20 chunks
constexpr int PW = 7;         // fused fallback: producer waves
constexpr int SLOTS = 4;      // fused fallback: stage slots per producer wave

// gather kernel geometry
constexpr int GW = 2;            // waves per gather block
constexpr int GNR = 10;          // rows (slots) per wave, all in flight at once
constexpr int GROWS = GW * GNR;  // 20 rows per gather block
constexpr int GBLK = Tc / GROWS; // 50 gather blocks per batch elem

// scan fill: CH rows x 512 B (bf16) = 25.6 KB per chunk = 25 x 1KB dma16
constexpr int FPC = CH * Uc * 2 / 1024; // 25 dma16 per chunk

#define NEG_INF_F (-100000.0f)
#define LOG2E_F 1.44269504088896340736f
#define LN2_F 0.69314718055994530942f
#define DEAD_F (-1.0e9f)
#define EBIAS 30  // renorm target: lane max ~2^30

// s_waitcnt immediate: vmcnt(n) only (vmcnt[3:0]@[3:0], vmcnt[5:4]@[15:14],
// exp@[6:4]=7, lgkm@[11:8]=0xF). n must be a compile-time constant.
#define WAITVM(n) __builtin_amdgcn_s_waitcnt(((n) & 15) | (((n) >> 4) << 14) | 0x0f70)

__device__ __forceinline__ float fexp2(float x) {
#if __has_builtin(__builtin_amdgcn_exp2f)
    return __builtin_amdgcn_exp2f(x);
#else
    return __expf(x * LN2_F);
#endif
}
__device__ __forceinline__ float flog2(float x) {
#if __has_builtin(__builtin_amdgcn_logf)
    return __builtin_amdgcn_logf(x);
#else
    return __logf(x) * LOG2E_F;
#endif
}

// log2-domain logadd: log2(2^x + 2^y)
__device__ __forceinline__ float l2add(float x, float y) {
    float m = fmaxf(x, y);
    float p = fexp2(-fabsf(x - y));
    return m + flog2(1.0f + p);
}

// Whole-wave shift-up-by-1 via DPP wave_shr:1 (full-rate VALU op).
__device__ __forceinline__ float waveshr1(float x, float lane0val) {
    return __int_as_float(__builtin_amdgcn_update_dpp(
        __float_as_int(lane0val), __float_as_int(x),
        0x138 /* wave_shr:1 */, 0xF, 0xF, false));
}
__device__ __forceinline__ int waveshr1_i(int x) {
    return __builtin_amdgcn_update_dpp(x, x, 0x138, 0xF, 0xF, false);
}

// unpack 4 bf16 (packed uint2, memory order) -> float4
__device__ __forceinline__ float4 unbf(uint2 u) {
    float4 f;
    f.x = __uint_as_float(u.x << 16);
    f.y = __uint_as_float(u.x & 0xffff0000u);
    f.z = __uint_as_float(u.y << 16);
    f.w = __uint_as_float(u.y & 0xffff0000u);
    return f;
}
// pack two f32 -> two bf16 (RNE), b in high half
__device__ __forceinline__ unsigned int bfpack(float a, float b) {
    unsigned int xa = __float_as_uint(a), xb = __float_as_uint(b);
    xa = (xa + 0x7fffu + ((xa >> 16) & 1u)) >> 16;
    xb = (xb + 0x7fffu + ((xb >> 16) & 1u)) & 0xffff0000u;
    return xa | xb;
}

// LINEAR-domain HMM step, f32 mantissa with per-lane scale (value = rr*2^e).
__device__ __forceinline__ void hmm_step_f32(float rr[4], const float4 ev,
                                             float sc_d) {
    float nb0 = waveshr1(rr[3], 0.0f) * sc_d; // lane0: no predecessor -> 0
    float s0 = rr[0] + nb0;
    float s1 = rr[1] + rr[0];
    float s2 = rr[2] + rr[1];
    float s3 = rr[3] + rr[2];
    rr[0] = s0 * ev.x;
    rr[1] = s1 * ev.y;
    rr[2] = s2 * ev.z;
    rr[3] = s3 * ev.w;
}

// log2-domain HMM step (fallback kernel only)
__device__ __forceinline__ void hmm_step(float rr[4], const float4 ev) {
    float nb0 = waveshr1(rr[3], DEAD_F);
    float e[4] = {ev.x, ev.y, ev.z, ev.w};
    float nb[4] = {nb0, rr[0], rr[1], rr[2]};
#pragma unroll
    for (int c = 0; c < 4; ++c) {
        float x = rr[c], y = nb[c];
        float m = fmaxf(x, y);
        float p = fexp2(-fabsf(x - y));
        float me = m + e[c];
        rr[c] = me + flog2(1.0f + p);
    }
}

// async global->LDS DMA of 16 B/lane (1 KB per wave-instruction).
// AUX = CPol: 0 default; 2 = SLC/NT (evict-first, for single-use streams).
template <int AUX>
__device__ __forceinline__ void dma16x(const void* gsrc, void* lds, int lane) {
    typedef const __attribute__((address_space(1))) unsigned int* gp_t;
    typedef __attribute__((address_space(3))) unsigned int* lp_t;
    __builtin_amdgcn_global_load_lds((gp_t)((const char*)gsrc + 16 * lane),
                                     (lp_t)lds, 16, 0, AUX);
}
__device__ __forceinline__ void dma16(const void* g, void* l, int lane) {
    dma16x<0>(g, l, lane);
}
__device__ __forceinline__ void dma16nt(const void* g, void* l, int lane) {
    dma16x<2>(g, l, lane);
}

// ---------------------------------------------------------------------------
// Kernel A: gather + transform emissions to LINEAR bf16 EL[b][t][u].
// EL = 2^(lp*log2e + off); masked (u>=Uv or t>=Tv) -> 0. lp reads are NT
// (single-use streaming, round-9 win); EL writes are ALSO NT (written once,
// read once by scan which misses to HBM anyway per FETCH_SIZE -- evict-first
// avoids 32 MB of dirty-line churn against the poison writeback).
// ---------------------------------------------------------------------------
__global__ __launch_bounds__(128, 2) void gather_kernel(
    const float* __restrict__ lp, const float* __restrict__ lens,
    const int* __restrict__ phns, const float* __restrict__ phn_lens,
    unsigned short* __restrict__ el) {
    __shared__ float stage[GW][GNR][Vc]; // 40 KB -> 4 blocks/CU
    const int b = blockIdx.x;
    const int t0 = blockIdx.y * GROWS;
    const int tid = threadIdx.x;
    const int wave = tid >> 6;
    const int lane = tid & 63;
    const int Tv = (int)rintf(lens[b] * (float)Tc);
    const int Uv = (int)rintf(phn_lens[b] * (float)Uc);
    const float* lpb = lp + (size_t)b * Tc * Vc;
    unsigned short* elb = el + ((size_t)b * Tc + t0) * Uc;

    int col[4];
    float off[4];
    bool pv[4];
    int4 cc = *(const int4*)(phns + (size_t)b * Uc + 4 * lane);
    int c4[4] = {cc.x, cc.y, cc.z, cc.w};
#pragma unroll
    for (int c = 0; c < 4; ++c) {
        int v = c4[c];
        v = v < 0 ? 0 : (v > Vc - 1 ? Vc - 1 : v);
        col[c] = v;
        int i = 4 * lane + c;
        pv[c] = (i < Uv);
        off[c] = (i == Uv - 1) ? 0.0f : -1.0f; // transition const (log2 units)
    }

    float* stw = &stage[wave][0][0];
    // issue ALL row loads (2 x dma16 per row, 20 vmem ops in flight), NT
#pragma unroll
    for (int j = 0; j < GNR; ++j) {
        int r = wave + j * GW;
        const float* gsrc = lpb + (size_t)(t0 + r) * Vc;
        float* st = stw + j * Vc;
        dma16nt(gsrc, st, lane);             // floats [0..255]
        dma16nt(gsrc + 256, st + 256, lane); // floats [256..511]
    }

    auto do_rows = [&](int j0) {
#pragma unroll
        for (int j = j0; j < j0 + GNR / 2; ++j) {
            int r = wave + j * GW;
            const bool tv = (t0 + r) < Tv;
            const float* st = stw + j * Vc;
            float ev[4];
#pragma unroll
            for (int c = 0; c < 4; ++c) {
                float e = st[col[c]]; // random-bank ds_read_b32 (cheap)
                ev[c] = (pv[c] && tv) ? fexp2(fmaf(e, LOG2E_F, off[c])) : 0.0f;
            }
            unsigned long long pk =
                (unsigned long long)bfpack(ev[0], ev[1]) |
                ((unsigned long long)bfpack(ev[2], ev[3]) << 32);
            __builtin_nontemporal_store(
                pk, (unsigned long long*)((char*)elb + (size_t)r * Uc * 2 +
                                          8 * lane));
        }
    };

    WAITVM(10); // first 10 loads (rows j=0..4) landed
    do_rows(0);
    WAITVM(0); // rest landed
    do_rows(GNR / 2);
}

// ---------------------------------------------------------------------------
// Kernel B: linear-domain scan over bf16 EL, 2-wave parity fill + 2-STEP
// OPERATOR COMBINE (round-11, verified). EL fill DMAs are NT: each byte is
// read exactly once; no reason to allocate 32 MB in L2/L3 during the scan.
//   r_i(t+2) = a_i r_i + b_i r_{i-1} + c_i r_{i-2},
//   a=E2*E1, b=E2*(E1+E1left), c=E2*E1left
// Renorm every 8 steps; per-lane exponent, exact pow2 scaling; zero lanes
// adopt left neighbor's exponent.
// ---------------------------------------------------------------------------
__global__ __launch_bounds__(128, 1) void scan_kernel(
    const unsigned short* __restrict__ el, const float* __restrict__ phn_lens,
    float* __restrict__ out) {
    __shared__ unsigned short ebuf[4][CH][Uc]; // 102.4 KB quad buffer
    const int b = blockIdx.x;
    const int tid = threadIdx.x;
    const int wave = tid >> 6;
    const int lane = tid & 63;
    const int Uv = (int)rintf(phn_lens[b] * (float)Uc);
    const char* eb = (const char*)(el + (size_t)b * Tc * Uc);
    float rr[4];
    int e = 0;         // per-lane scale: true value = rr * 2^e
    float sc_d = 1.0f; // 2^(e_left - e), refreshed at each renorm

    auto fill = [&](int k) {
        const char* src = eb + (size_t)k * CH * Uc * 2;
        char* dst = (char*)&ebuf[k & 3][0][0];
#pragma unroll
        for (int i = 0; i < FPC; ++i)
            dma16nt(src + i * 1024, dst + i * 1024, lane);
    };

    auto renorm = [&]() {
        float m = fmaxf(fmaxf(rr[0], rr[1]), fmaxf(rr[2], rr[3]));
        int ep_old = waveshr1_i(e); // left neighbor's e (lane0: own)
        bool nz = (m > 0.0f);
        int ik = ((__float_as_int(m) >> 23) & 255) - 127 - EBIAS;
        ik = ik < -96 ? -96 : (ik > 96 ? 96 : ik);
        const float sc = __int_as_float((127 - ik) << 23); // exact 2^-ik
        rr[0] *= sc; rr[1] *= sc; rr[2] *= sc; rr[3] *= sc;
        e = nz ? (e + ik) : ep_old; // zero lanes adopt left's exponent
        int ep = waveshr1_i(e);
        int d = ep - e;
        int dc = d < -126 ? -126 : (d > 127 ? 127 : d);
        float sd = __int_as_float((127 + dc) << 23); // exact 2^d
        sc_d = (d < -126) ? 0.0f : sd; // mass < 2^-149 rel -> truly 0
    };

    // two combined HMM steps: E1 = row t+1, E2 = row t+2
    auto pairstep = [&](const float4 E1, const float4 E2) {
        // ---- coefficients (emission-only, off the recurrent chain) ----
        float e1m0 = waveshr1(E1.w, 0.0f); // left lane's E1[3]; lane0 -> 0
        float a0 = E2.x * E1.x, a1 = E2.y * E1.y;
        float a2 = E2.z * E1.z, a3 = E2.w * E1.w;
        float b0 = E2.x * (E1.x + e1m0);
        float b1 = E2.y * (E1.y + E1.x);
        float b2 = E2.z * (E1.z + E1.y);
        float b3 = E2.w * (E1.w + E1.z);
        float c0 = E2.x * e1m0;
        float c1 = E2.y * E1.x;
        float c2 = E2.z * E1.y;
        float c3 = E2.w * E1.z;
        // ---- recurrent evaluation (short chain) ----
        float rl3 = waveshr1(rr[3], 0.0f) * sc_d; // left r[3]
        float rl2 = waveshr1(rr[2], 0.0f) * sc_d; // left r[2]
        float n0 = fmaf(a0, rr[0], fmaf(b0, rl3, c0 * rl2));
        float n1 = fmaf(a1, rr[1], fmaf(b1, rr[0], c1 * rl3));
        float n2 = fmaf(a2, rr[2], fmaf(b2, rr[1], c2 * rr[0]));
        float n3 = fmaf(a3, rr[3], fmaf(b3, rr[2], c3 * rr[1]));
        rr[0] = n0; rr[1] = n1; rr[2] = n2; rr[3] = n3;
    };

    auto consume = [&](int k) {
        const uint2* base = (const uint2*)&ebuf[k & 3][0][0] + lane; // 64/row
        int r0row = 0;
        if (k == 0) {
            float4 e0 = unbf(base[0]);
            float ea[4] = {e0.x, e0.y, e0.z, e0.w};
#pragma unroll
            for (int c = 0; c < 4; ++c)
                rr[c] = (4 * lane + c == 0) ? ea[c] : 0.0f; // pi * EL(0)
            hmm_step_f32(rr, unbf(base[64]), sc_d);         // row 1 single
            r0row = 2;
        }
        // group of 4 pairs (8 rows) then renorm; 6 groups cover 48 rows.
        auto group4 = [&](int r) {
            uint2 w[8];
#pragma unroll
            for (int i = 0; i < 8; ++i) w[i] = base[(r + i) * 64];
#pragma unroll
            for (int p = 0; p < 4; ++p)
                pairstep(unbf(w[2 * p]), unbf(w[2 * p + 1]));
            renorm();
        };
#pragma unroll
        for (int g = 0; g < 6; ++g) group4(r0row + g * 8);
        if (r0row == 0) { // k>0: rows 48,49 remain (one pair)
            pairstep(unbf(base[48 * 64]), unbf(base[49 * 64]));
            renorm();
        }
    };

    WAITVM(0); // quiesce prologue vector loads before counting vmcnt
    if (wave == 0) {
        fill(0); fill(2); // even chunks, buffers 0/2, own vmcnt
    } else {
        fill(1); fill(3); // odd chunks, buffers 1/3, own vmcnt
    }

    for (int k = 0; k < NCH; ++k) {
        if ((k & 1) == 0) {
            if (wave == 0) {
                if (k < NCH - 2) WAITVM(FPC); // fill(k) retired; k+2 in flight
                else WAITVM(0);
                consume(k);
                if (k + 4 < NCH) fill(k + 4); // buffer k&3 just freed
            }
        } else {
            if (wave == 1) {
                if (k < NCH - 2) WAITVM(FPC); // fill(k) retired; k+2 in flight
                else WAITVM(0);
            }
            __syncthreads(); // A: chunk k's LDS data visible to wave 0
            if (wave == 0) consume(k);
            __syncthreads(); // B: consume(k) done; buffer k&3 free
            if (wave == 1 && k + 4 < NCH) fill(k + 4);
        }
    }

    if (wave != 0) return;
    // undo per-state shift (x2 on non-last states), per-lane log2 + e,
    // then wave-wide logsumexp (log2 domain), back to nats.
    float a = 0.0f;
#pragma unroll
    for (int c = 0; c < 4; ++c)
        a += rr[c] * ((4 * lane + c == Uv - 1) ? 1.0f : 2.0f);
    float v = (a > 0.0f) ? (flog2(a) + (float)e) : -1.0e30f;
#pragma unroll
    for (int o = 32; o >= 1; o >>= 1) {
        float t = __shfl_xor(v, o, 64);
        v = l2add(v, t);
    }
    if (lane == 0) out[b] = v * LN2_F;
}

// ---------------------------------------------------------------------------
// Fallback: fused single-kernel log2-domain version (workspace too small).
// Passed verification (absmax 0.0) in earlier rounds.
// ---------------------------------------------------------------------------
__global__ __launch_bounds__(512, 1) void fused_hmm_kernel(
    const float* __restrict__ lp, const float* __restrict__ lens,
    const int* __restrict__ phns, const float* __restrict__ phn_lens,
    float* __restrict__ out) {
    __shared__ float ebuf[2][CH][Uc];      // 100 KB
    __shared__ float stage[PW][SLOTS][Vc]; // 56 KB
    const int b = blockIdx.x;
    const int tid = threadIdx.x;
    const int wave = tid >> 6;
    const int lane = tid & 63;
    const int Tv = (int)rintf(lens[b] * (float)Tc);
    const int Uv = (int)rintf(phn_lens[b] * (float)Uc);
    const float* lpb = lp + (size_t)b * Tc * Vc;

    int col[4];
    float off[4];
    bool pv[4];
    float rr[4];

    if (wave > 0) {
        int4 cc = *(const int4*)(phns + (size_t)b * Uc + 4 * lane);
        int c4[4] = {cc.x, cc.y, cc.z, cc.w};
#pragma unroll
        for (int c = 0; c < 4; ++c) {
            int v = c4[c];
            v = v < 0 ? 0 : (v > Vc - 1 ? Vc - 1 : v);
            col[c] = v;
            int i = 4 * lane + c;
            pv[c] = (i < Uv);
            off[c] = (i == Uv - 1) ? 0.0f : -1.0f;
        }
    }

    auto fill = [&](int k) {
        float* dst = &ebuf[k & 1][0][0];
        const int tb = k * CH;
        const int r0 = wave - 1;
        float* stw = &stage[wave - 1][0][0];
#pragma unroll
        for (int half = 0; half < 2; ++half) {
#pragma unroll
            for (int jj = 0; jj < SLOTS; ++jj) {
                int r = r0 + (half * SLOTS + jj) * PW;
                if (r < CH) {
                    const float* gsrc = lpb + (size_t)(tb + r) * Vc;
                    float* st = stw + jj * Vc;
                    dma16(gsrc, st, lane);
                    dma16(gsrc + 256, st + 256, lane);
                }
            }
            WAITVM(0);
#pragma unroll
            for (int jj = 0; jj < SLOTS; ++jj) {
                int r = r0 + (half * SLOTS + jj) * PW;
                if (r < CH) {
                    const bool tv = (tb + r) < Tv;
                    const float* st = stw + jj * Vc;
                    float ev[4];
#pragma unroll
                    for (int c = 0; c < 4; ++c) {
                        float e = st[col[c]];
                        ev[c] = (pv[c] && tv) ? fmaf(e, LOG2E_F, off[c])
                                              : (NEG_INF_F * LOG2E_F + off[c]);
                    }
                    *(float4*)(dst + r * Uc + 4 * lane) =
                        make_float4(ev[0], ev[1], ev[2], ev[3]);
                }
            }
        }
    };

    auto consume = [&](int k) {
        const float4* base = (const float4*)&ebuf[k & 1][0][0] + lane;
        int r = 0;
        if (k == 0) {
            float4 e0 = base[0];
            float ea[4] = {e0.x, e0.y, e0.z, e0.w};
#pragma unroll
            for (int c = 0; c < 4; ++c)
                rr[c] = ((4 * lane + c == 0) ? 0.0f : DEAD_F) + ea[c];
            r = 1;
        }
        float4 q0, q1, q2, q3;
        if (r + 0 < CH) q0 = base[(r + 0) * 64];
        if (r + 1 < CH) q1 = base[(r + 1) * 64];
        if (r + 2 < CH) q2 = base[(r + 2) * 64];
        if (r + 3 < CH) q3 = base[(r + 3) * 64];
        while (r + 4 <= CH) {
            float4 e0 = q0, e1 = q1, e2 = q2, e3 = q3;
            if (r + 4 < CH) q0 = base[(r + 4) * 64];
            if (r + 5 < CH) q1 = base[(r + 5) * 64];
            if (r + 6 < CH) q2 = base[(r + 6) * 64];
            if (r + 7 < CH) q3 = base[(r + 7) * 64];
            hmm_step(rr, e0);
            hmm_step(rr, e1);
            hmm_step(rr, e2);
            hmm_step(rr, e3);
            r += 4;
        }
        if (r + 0 < CH) hmm_step(rr, q0);
        if (r + 1 < CH) hmm_step(rr, q1);
        if (r + 2 < CH) hmm_step(rr, q2);
    };

    if (wave > 0) fill(0);
    __syncthreads();
    for (int k = 0; k < NCH; ++k) {
        if (wave > 0) {
            if (k + 1 < NCH) fill(k + 1);
        } else {
            consume(k);
        }
        __syncthreads();
    }

    if (wave == 0) {
        float a[4];
#pragma unroll
        for (int c = 0; c < 4; ++c)
            a[c] = rr[c] + ((4 * lane + c == Uv - 1) ? 0.0f : 1.0f);
        float r2 = l2add(l2add(a[0], a[1]), l2add(a[2], a[3]));
#pragma unroll
        for (int o = 32; o >= 1; o >>= 1) {
            float t = __shfl_xor(r2, o, 64);
            r2 = l2add(r2, t);
        }
        if (lane == 0) out[b] = r2 * LN2_F;
    }
}

extern "C" void kernel_launch(void* const* d_in, const int* in_sizes, int n_in,
                              void* d_out, int out_size, void* d_ws, size_t ws_size,
                              hipStream_t stream) {
    const float* lp = (const float*)d_in[0];
    const float* lens = (const float*)d_in[1];
    const int* phns = (const int*)d_in[2];
    const float* phn_lens = (const float*)d_in[3];
    float* out = (float*)d_out;
    (void)in_sizes; (void)n_in; (void)out_size;

    const size_t need = (size_t)Bc * Tc * Uc * 2; // 32.8 MB (bf16)
    if (d_ws != nullptr && ws_size >= need) {
        unsigned short* el = (unsigned short*)d_ws;
        gather_kernel<<<dim3(Bc, GBLK), 128, 0, stream>>>(lp, lens, phns,
                                                          phn_lens, el);
        scan_kernel<<<Bc, 128, 0, stream>>>(el, phn_lens, out);
    } else {
        fused_hmm_kernel<<<Bc, 512, 0, stream>>>(lp, lens, phns, phn_lens, out);
    }
}

// Round 13
// 239.163 us; speedup vs baseline: 1.0360x; 1.0360x over previous
//
#include <hip/hip_runtime.h>
#include <math.h>

// Problem dims (fixed by setup_inputs)
constexpr int Bc = 64;
constexpr int Tc = 1000;
constexpr int Vc = 512;
constexpr int Uc = 256;
constexpr int CH = 50;        // t-rows per LDS chunk (scan)
constexpr int NCH = Tc / CH;  // 20 chunks
constexpr int PW = 7;         // fused fallback: producer waves
constexpr int SLOTS = 4;      // fused fallback: stage slots per producer wave

// gather kernel geometry
constexpr int GW = 2;            // waves per gather block
constexpr int GNR = 10;          // rows (slots) per wave, all in flight at once
constexpr int GROWS = GW * GNR;  // 20 rows per gather block
constexpr int GBLK = Tc / GROWS; // 50 gather blocks per batch elem

// scan fill: CH rows x 512 B (bf16) = 25.6 KB per chunk = 25 x 1KB dma16
constexpr int FPC = CH * Uc * 2 / 1024; // 25 dma16 per chunk

#define NEG_INF_F (-100000.0f)
#define LOG2E_F 1.44269504088896340736f
#define LN2_F 0.69314718055994530942f
#define DEAD_F (-1.0e9f)
#define EBIAS 30  // renorm target: lane max ~2^30

// s_waitcnt immediate: vmcnt(n) only (vmcnt[3:0]@[3:0], vmcnt[5:4]@[15:14],
// exp@[6:4]=7, lgkm@[11:8]=0xF). n must be a compile-time constant.
#define WAITVM(n) __builtin_amdgcn_s_waitcnt(((n) & 15) | (((n) >> 4) << 14) | 0x0f70)

__device__ __forceinline__ float fexp2(float x) {
#if __has_builtin(__builtin_amdgcn_exp2f)
    return __builtin_amdgcn_exp2f(x);
#else
    return __expf(x * LN2_F);
#endif
}
__device__ __forceinline__ float flog2(float x) {
#if __has_builtin(__builtin_amdgcn_logf)
    return __builtin_amdgcn_logf(x);
#else
    return __logf(x) * LOG2E_F;
#endif
}

// log2-domain logadd: log2(2^x + 2^y)
__device__ __forceinline__ float l2add(float x, float y) {
    float m = fmaxf(x, y);
    float p = fexp2(-fabsf(x - y));
    return m + flog2(1.0f + p);
}

// Whole-wave shift-up-by-1 via DPP wave_shr:1 (full-rate VALU op).
__device__ __forceinline__ float waveshr1(float x, float lane0val) {
    return __int_as_float(__builtin_amdgcn_update_dpp(
        __float_as_int(lane0val), __float_as_int(x),
        0x138 /* wave_shr:1 */, 0xF, 0xF, false));
}
__device__ __forceinline__ int waveshr1_i(int x) {
    return __builtin_amdgcn_update_dpp(x, x, 0x138, 0xF, 0xF, false);
}

// unpack 4 bf16 (packed uint2, memory order) -> float4
__device__ __forceinline__ float4 unbf(uint2 u) {
    float4 f;
    f.x = __uint_as_float(u.x << 16);
    f.y = __uint_as_float(u.x & 0xffff0000u);
    f.z = __uint_as_float(u.y << 16);
    f.w = __uint_as_float(u.y & 0xffff0000u);
    return f;
}
// pack two f32 -> two bf16 (RNE), b in high half
__device__ __forceinline__ unsigned int bfpack(float a, float b) {
    unsigned int xa = __float_as_uint(a), xb = __float_as_uint(b);
    xa = (xa + 0x7fffu + ((xa >> 16) & 1u)) >> 16;
    xb = (xb + 0x7fffu + ((xb >> 16) & 1u)) & 0xffff0000u;
    return xa | xb;
}

// LINEAR-domain HMM step, f32 mantissa with per-lane scale (value = rr*2^e).
__device__ __forceinline__ void hmm_step_f32(float rr[4], const float4 ev,
                                             float sc_d) {
    float nb0 = waveshr1(rr[3], 0.0f) * sc_d; // lane0: no predecessor -> 0
    float s0 = rr[0] + nb0;
    float s1 = rr[1] + rr[0];
    float s2 = rr[2] + rr[1];
    float s3 = rr[3] + rr[2];
    rr[0] = s0 * ev.x;
    rr[1] = s1 * ev.y;
    rr[2] = s2 * ev.z;
    rr[3] = s3 * ev.w;
}

// log2-domain HMM step (fallback kernel only)
__device__ __forceinline__ void hmm_step(float rr[4], const float4 ev) {
    float nb0 = waveshr1(rr[3], DEAD_F);
    float e[4] = {ev.x, ev.y, ev.z, ev.w};
    float nb[4] = {nb0, rr[0], rr[1], rr[2]};
#pragma unroll
    for (int c = 0; c < 4; ++c) {
        float x = rr[c], y = nb[c];
        float m = fmaxf(x, y);
        float p = fexp2(-fabsf(x - y));
        float me = m + e[c];
        rr[c] = me + flog2(1.0f + p);
    }
}

// async global->LDS DMA of 16 B/lane (1 KB per wave-instruction).
// AUX = CPol: 0 default; 2 = SLC/NT (evict-first, for single-use streams).
template <int AUX>
__device__ __forceinline__ void dma16x(const void* gsrc, void* lds, int lane) {
    typedef const __attribute__((address_space(1))) unsigned int* gp_t;
    typedef __attribute__((address_space(3))) unsigned int* lp_t;
    __builtin_amdgcn_global_load_lds((gp_t)((const char*)gsrc + 16 * lane),
                                     (lp_t)lds, 16, 0, AUX);
}
__device__ __forceinline__ void dma16(const void* g, void* l, int lane) {
    dma16x<0>(g, l, lane);
}
__device__ __forceinline__ void dma16nt(const void* g, void* l, int lane) {
    dma16x<2>(g, l, lane);
}

// ---------------------------------------------------------------------------
// Kernel A: gather + transform emissions to LINEAR bf16 EL[b][t][u].
// EL = 2^(lp*log2e + off); masked (u>=Uv or t>=Tv) -> 0. lp reads are NT
// (single-use streaming, round-9 win: -9 us); EL writes NORMAL policy
// (round-12 A/B: NT on EL path costs +7 us -- keep cache-resident).
// ---------------------------------------------------------------------------
__global__ __launch_bounds__(128, 2) void gather_kernel(
    const float* __restrict__ lp, const float* __restrict__ lens,
    const int* __restrict__ phns, const float* __restrict__ phn_lens,
    unsigned short* __restrict__ el) {
    __shared__ float stage[GW][GNR][Vc]; // 40 KB -> 4 blocks/CU
    const int b = blockIdx.x;
    const int t0 = blockIdx.y * GROWS;
    const int tid = threadIdx.x;
    const int wave = tid >> 6;
    const int lane = tid & 63;
    const int Tv = (int)rintf(lens[b] * (float)Tc);
    const int Uv = (int)rintf(phn_lens[b] * (float)Uc);
    const float* lpb = lp + (size_t)b * Tc * Vc;
    unsigned short* elb = el + ((size_t)b * Tc + t0) * Uc;

    int col[4];
    float off[4];
    bool pv[4];
    int4 cc = *(const int4*)(phns + (size_t)b * Uc + 4 * lane);
    int c4[4] = {cc.x, cc.y, cc.z, cc.w};
#pragma unroll
    for (int c = 0; c < 4; ++c) {
        int v = c4[c];
        v = v < 0 ? 0 : (v > Vc - 1 ? Vc - 1 : v);
        col[c] = v;
        int i = 4 * lane + c;
        pv[c] = (i < Uv);
        off[c] = (i == Uv - 1) ? 0.0f : -1.0f; // transition const (log2 units)
    }

    float* stw = &stage[wave][0][0];
    // issue ALL row loads (2 x dma16 per row, 20 vmem ops in flight), NT
#pragma unroll
    for (int j = 0; j < GNR; ++j) {
        int r = wave + j * GW;
        const float* gsrc = lpb + (size_t)(t0 + r) * Vc;
        float* st = stw + j * Vc;
        dma16nt(gsrc, st, lane);             // floats [0..255]
        dma16nt(gsrc + 256, st + 256, lane); // floats [256..511]
    }

    auto do_rows = [&](int j0) {
#pragma unroll
        for (int j = j0; j < j0 + GNR / 2; ++j) {
            int r = wave + j * GW;
            const bool tv = (t0 + r) < Tv;
            const float* st = stw + j * Vc;
            float ev[4];
#pragma unroll
            for (int c = 0; c < 4; ++c) {
                float e = st[col[c]]; // random-bank ds_read_b32 (cheap)
                ev[c] = (pv[c] && tv) ? fexp2(fmaf(e, LOG2E_F, off[c])) : 0.0f;
            }
            uint2 pk;
            pk.x = bfpack(ev[0], ev[1]);
            pk.y = bfpack(ev[2], ev[3]);
            *(uint2*)((char*)elb + (size_t)r * Uc * 2 + 8 * lane) = pk;
        }
    };

    WAITVM(10); // first 10 loads (rows j=0..4) landed
    do_rows(0);
    WAITVM(0); // rest landed
    do_rows(GNR / 2);
}

// ---------------------------------------------------------------------------
// Kernel B: linear-domain scan over bf16 EL, 2-wave parity fill + 2-STEP
// OPERATOR COMBINE. Two HMM steps compose to a band-2 recurrence
//   r_i(t+2) = a_i r_i + b_i r_{i-1} + c_i r_{i-2},
//   a=E2*E1, b=E2*(E1+E1left), c=E2*E1left
// Coefficients depend only on emissions -> computed OFF the recurrent chain;
// the chain is one fma tree per TWO steps. Renorm every 8 steps (4 pairs):
// worst-case growth 64 bits << 97-bit headroom over 2^EBIAS; adoption-lag
// d <= one period drift <= 64 < 126 so sc_d stays finite. Fill DMAs use
// DEFAULT cache policy (round-12 A/B: NT here regressed).
// ---------------------------------------------------------------------------
__global__ __launch_bounds__(128, 1) void scan_kernel(
    const unsigned short* __restrict__ el, const float* __restrict__ phn_lens,
    float* __restrict__ out) {
    __shared__ unsigned short ebuf[4][CH][Uc]; // 102.4 KB quad buffer
    const int b = blockIdx.x;
    const int tid = threadIdx.x;
    const int wave = tid >> 6;
    const int lane = tid & 63;
    const int Uv = (int)rintf(phn_lens[b] * (float)Uc);
    const char* eb = (const char*)(el + (size_t)b * Tc * Uc);
    float rr[4];
    int e = 0;         // per-lane scale: true value = rr * 2^e
    float sc_d = 1.0f; // 2^(e_left - e), refreshed at each renorm

    auto fill = [&](int k) {
        const char* src = eb + (size_t)k * CH * Uc * 2;
        char* dst = (char*)&ebuf[k & 3][0][0];
#pragma unroll
        for (int i = 0; i < FPC; ++i)
            dma16(src + i * 1024, dst + i * 1024, lane);
    };

    auto renorm = [&]() {
        float m = fmaxf(fmaxf(rr[0], rr[1]), fmaxf(rr[2], rr[3]));
        int ep_old = waveshr1_i(e); // left neighbor's e (lane0: own)
        bool nz = (m > 0.0f);
        int ik = ((__float_as_int(m) >> 23) & 255) - 127 - EBIAS;
        ik = ik < -96 ? -96 : (ik > 96 ? 96 : ik);
        const float sc = __int_as_float((127 - ik) << 23); // exact 2^-ik
        rr[0] *= sc; rr[1] *= sc; rr[2] *= sc; rr[3] *= sc;
        e = nz ? (e + ik) : ep_old; // zero lanes adopt left's exponent
        int ep = waveshr1_i(e);
        int d = ep - e;
        int dc = d < -126 ? -126 : (d > 127 ? 127 : d);
        float sd = __int_as_float((127 + dc) << 23); // exact 2^d
        sc_d = (d < -126) ? 0.0f : sd; // mass < 2^-149 rel -> truly 0
    };

    // two combined HMM steps: E1 = row t+1, E2 = row t+2
    auto pairstep = [&](const float4 E1, const float4 E2) {
        // ---- coefficients (emission-only, off the recurrent chain) ----
        float e1m0 = waveshr1(E1.w, 0.0f); // left lane's E1[3]; lane0 -> 0
        float a0 = E2.x * E1.x, a1 = E2.y * E1.y;
        float a2 = E2.z * E1.z, a3 = E2.w * E1.w;
        float b0 = E2.x * (E1.x + e1m0);
        float b1 = E2.y * (E1.y + E1.x);
        float b2 = E2.z * (E1.z + E1.y);
        float b3 = E2.w * (E1.w + E1.z);
        float c0 = E2.x * e1m0;
        float c1 = E2.y * E1.x;
        float c2 = E2.z * E1.y;
        float c3 = E2.w * E1.z;
        // ---- recurrent evaluation (short chain) ----
        float rl3 = waveshr1(rr[3], 0.0f) * sc_d; // left r[3]
        float rl2 = waveshr1(rr[2], 0.0f) * sc_d; // left r[2]
        float n0 = fmaf(a0, rr[0], fmaf(b0, rl3, c0 * rl2));
        float n1 = fmaf(a1, rr[1], fmaf(b1, rr[0], c1 * rl3));
        float n2 = fmaf(a2, rr[2], fmaf(b2, rr[1], c2 * rr[0]));
        float n3 = fmaf(a3, rr[3], fmaf(b3, rr[2], c3 * rr[1]));
        rr[0] = n0; rr[1] = n1; rr[2] = n2; rr[3] = n3;
    };

    auto consume = [&](int k) {
        const uint2* base = (const uint2*)&ebuf[k & 3][0][0] + lane; // 64/row
        int r0row = 0;
        if (k == 0) {
            float4 e0 = unbf(base[0]);
            float ea[4] = {e0.x, e0.y, e0.z, e0.w};
#pragma unroll
            for (int c = 0; c < 4; ++c)
                rr[c] = (4 * lane + c == 0) ? ea[c] : 0.0f; // pi * EL(0)
            hmm_step_f32(rr, unbf(base[64]), sc_d);         // row 1 single
            r0row = 2;
        }
        // group of 4 pairs (8 rows) then renorm; 6 groups cover 48 rows.
        auto group4 = [&](int r) {
            uint2 w[8];
#pragma unroll
            for (int i = 0; i < 8; ++i) w[i] = base[(r + i) * 64];
#pragma unroll
            for (int p = 0; p < 4; ++p)
                pairstep(unbf(w[2 * p]), unbf(w[2 * p + 1]));
            renorm();
        };
#pragma unroll
        for (int g = 0; g < 6; ++g) group4(r0row + g * 8);
        if (r0row == 0) { // k>0: rows 48,49 remain (one pair)
            pairstep(unbf(base[48 * 64]), unbf(base[49 * 64]));
            renorm();
        }
    };

    WAITVM(0); // quiesce prologue vector loads before counting vmcnt
    if (wave == 0) {
        fill(0); fill(2); // even chunks, buffers 0/2, own vmcnt
    } else {
        fill(1); fill(3); // odd chunks, buffers 1/3, own vmcnt
    }

    for (int k = 0; k < NCH; ++k) {
        if ((k & 1) == 0) {
            if (wave == 0) {
                if (k < NCH - 2) WAITVM(FPC); // fill(k) retired; k+2 in flight
                else WAITVM(0);
                consume(k);
                if (k + 4 < NCH) fill(k + 4); // buffer k&3 just freed
            }
        } else {
            if (wave == 1) {
                if (k < NCH - 2) WAITVM(FPC); // fill(k) retired; k+2 in flight
                else WAITVM(0);
            }
            __syncthreads(); // A: chunk k's LDS data visible to wave 0
            if (wave == 0) consume(k);
            __syncthreads(); // B: consume(k) done; buffer k&3 free
            if (wave == 1 && k + 4 < NCH) fill(k + 4);
        }
    }

    if (wave != 0) return;
    // undo per-state shift (x2 on non-last states), per-lane log2 + e,
    // then wave-wide logsumexp (log2 domain), back to nats.
    float a = 0.0f;
#pragma unroll
    for (int c = 0; c < 4; ++c)
        a += rr[c] * ((4 * lane + c == Uv - 1) ? 1.0f : 2.0f);
    float v = (a > 0.0f) ? (flog2(a) + (float)e) : -1.0e30f;
#pragma unroll
    for (int o = 32; o >= 1; o >>= 1) {
        float t = __shfl_xor(v, o, 64);
        v = l2add(v, t);
    }
    if (lane == 0) out[b] = v * LN2_F;
}

// ---------------------------------------------------------------------------
// Fallback: fused single-kernel log2-domain version (workspace too small).
// Passed verification (absmax 0.0) in earlier rounds.
// ---------------------------------------------------------------------------
__global__ __launch_bounds__(512, 1) void fused_hmm_kernel(
    const float* __restrict__ lp, const float* __restrict__ lens,
    const int* __restrict__ phns, const float* __restrict__ phn_lens,
    float* __restrict__ out) {
    __shared__ float ebuf[2][CH][Uc];      // 100 KB
    __shared__ float stage[PW][SLOTS][Vc]; // 56 KB
    const int b = blockIdx.x;
    const int tid = threadIdx.x;
    const int wave = tid >> 6;
    const int lane = tid & 63;
    const int Tv = (int)rintf(lens[b] * (float)Tc);
    const int Uv = (int)rintf(phn_lens[b] * (float)Uc);
    const float* lpb = lp + (size_t)b * Tc * Vc;

    int col[4];
    float off[4];
    bool pv[4];
    float rr[4];

    if (wave > 0) {
        int4 cc = *(const int4*)(phns + (size_t)b * Uc + 4 * lane);
        int c4[4] = {cc.x, cc.y, cc.z, cc.w};
#pragma unroll
        for (int c = 0; c < 4; ++c) {
            int v = c4[c];
            v = v < 0 ? 0 : (v > Vc - 1 ? Vc - 1 : v);
            col[c] = v;
            int i = 4 * lane + c;
            pv[c] = (i < Uv);
            off[c] = (i == Uv - 1) ? 0.0f : -1.0f;
        }
    }

    auto fill = [&](int k) {
        float* dst = &ebuf[k & 1][0][0];
        const int tb = k * CH;
        const int r0 = wave - 1;
        float* stw = &stage[wave - 1][0][0];
#pragma unroll
        for (int half = 0; half < 2; ++half) {
#pragma unroll
            for (int jj = 0; jj < SLOTS; ++jj) {
                int r = r0 + (half * SLOTS + jj) * PW;
                if (r < CH) {
                    const float* gsrc = lpb + (size_t)(tb + r) * Vc;
                    float* st = stw + jj * Vc;
                    dma16(gsrc, st, lane);
                    dma16(gsrc + 256, st + 256, lane);
                }
            }
            WAITVM(0);
#pragma unroll
            for (int jj = 0; jj < SLOTS; ++jj) {
                int r = r0 + (half * SLOTS + jj) * PW;
                if (r < CH) {
                    const bool tv = (tb + r) < Tv;
                    const float* st = stw + jj * Vc;
                    float ev[4];
#pragma unroll
                    for (int c = 0; c < 4; ++c) {
                        float e = st[col[c]];
                        ev[c] = (pv[c] && tv) ? fmaf(e, LOG2E_F, off[c])
                                              : (NEG_INF_F * LOG2E_F + off[c]);
                    }
                    *(float4*)(dst + r * Uc + 4 * lane) =
                        make_float4(ev[0], ev[1], ev[2], ev[3]);
                }
            }
        }
    };

    auto consume = [&](int k) {
        const float4* base = (const float4*)&ebuf[k & 1][0][0] + lane;
        int r = 0;
        if (k == 0) {
            float4 e0 = base[0];
            float ea[4] = {e0.x, e0.y, e0.z, e0.w};
#pragma unroll
            for (int c = 0; c < 4; ++c)
                rr[c] = ((4 * lane + c == 0) ? 0.0f : DEAD_F) + ea[c];
            r = 1;
        }
        float4 q0, q1, q2, q3;
        if (r + 0 < CH) q0 = base[(r + 0) * 64];
        if (r + 1 < CH) q1 = base[(r + 1) * 64];
        if (r + 2 < CH) q2 = base[(r + 2) * 64];
        if (r + 3 < CH) q3 = base[(r + 3) * 64];
        while (r + 4 <= CH) {
            float4 e0 = q0, e1 = q1, e2 = q2, e3 = q3;
            if (r + 4 < CH) q0 = base[(r + 4) * 64];
            if (r + 5 < CH) q1 = base[(r + 5) * 64];
            if (r + 6 < CH) q2 = base[(r + 6) * 64];
            if (r + 7 < CH) q3 = base[(r + 7) * 64];
            hmm_step(rr, e0);
            hmm_step(rr, e1);
            hmm_step(rr, e2);
            hmm_step(rr, e3);
            r += 4;
        }
        if (r + 0 < CH) hmm_step(rr, q0);
        if (r + 1 < CH) hmm_step(rr, q1);
        if (r + 2 < CH) hmm_step(rr, q2);
    };

    if (wave > 0) fill(0);
    __syncthreads();
    for (int k = 0; k < NCH; ++k) {
        if (wave > 0) {
            if (k + 1 < NCH) fill(k + 1);
        } else {
            consume(k);
        }
        __syncthreads();
    }

    if (wave == 0) {
        float a[4];
#pragma unroll
        for (int c = 0; c < 4; ++c)
            a[c] = rr[c] + ((4 * lane + c == Uv - 1) ? 0.0f : 1.0f);
        float r2 = l2add(l2add(a[0], a[1]), l2add(a[2], a[3]));
#pragma unroll
        for (int o = 32; o >= 1; o >>= 1) {
            float t = __shfl_xor(r2, o, 64);
            r2 = l2add(r2, t);
        }
        if (lane == 0) out[b] = r2 * LN2_F;
    }
}

extern "C" void kernel_launch(void* const* d_in, const int* in_sizes, int n_in,
                              void* d_out, int out_size, void* d_ws, size_t ws_size,
                              hipStream_t stream) {
    const float* lp = (const float*)d_in[0];
    const float* lens = (const float*)d_in[1];
    const int* phns = (const int*)d_in[2];
    const float* phn_lens = (const float*)d_in[3];
    float* out = (float*)d_out;
    (void)in_sizes; (void)n_in; (void)out_size;

    const size_t need = (size_t)Bc * Tc * Uc * 2; // 32.8 MB (bf16)
    if (d_ws != nullptr && ws_size >= need) {
        unsigned short* el = (unsigned short*)d_ws;
        gather_kernel<<<dim3(Bc, GBLK), 128, 0, stream>>>(lp, lens, phns,
                                                          phn_lens, el);
        scan_kernel<<<Bc, 128, 0, stream>>>(el, phn_lens, out);
    } else {
        fused_hmm_kernel<<<Bc, 512, 0, stream>>>(lp, lens, phns, phn_lens, out);
    }
}